// Round 1
// baseline (981.868 us; speedup 1.0000x reference)
//
#include <hip/hip_runtime.h>
#include <hip/hip_fp16.h>
#include <stdint.h>

typedef _Float16 f16;
typedef _Float16 f16x8 __attribute__((ext_vector_type(8)));
typedef float f32x4 __attribute__((ext_vector_type(4)));

#define NB 32768      // batch
#define LAYERS 6
#define AK 160        // HALF + COND
#define HID 1024

// async global->LDS, 16B per lane. LDS dest is wave-uniform base + lane*16.
__device__ __forceinline__ void async_copy16(const void* g, void* l) {
  __builtin_amdgcn_global_load_lds(
      (const __attribute__((address_space(1))) void*)g,
      (__attribute__((address_space(3))) void*)l, 16, 0, 0);
}

// ---------------------------------------------------------------------------
// prep: z = T (fp32 working state lives in d_out), log_det = 0,
// A[:, :32] = f16(T[:, 32:]) (layer0 unmasked), A[:, 32:160] = f16(cond)
// ---------------------------------------------------------------------------
__global__ void prep_batch(const float* __restrict__ T, const float* __restrict__ cond,
                           float* __restrict__ z, float* __restrict__ ld,
                           f16* __restrict__ A)
{
  const int S1 = NB * 64;
  const int S2 = S1 + NB;
  const int S3 = S2 + NB * 32;
  const int S4 = S3 + NB * 128;
  for (int i = blockIdx.x * blockDim.x + threadIdx.x; i < S4;
       i += gridDim.x * blockDim.x) {
    if (i < S1) {
      z[i] = T[i];
    } else if (i < S2) {
      ld[i - S1] = 0.0f;
    } else if (i < S3) {
      int r = i - S2;
      int row = r >> 5, j = r & 31;
      A[(size_t)row * AK + j] = (f16)T[row * 64 + 32 + j];
    } else {
      int r = i - S3;
      int row = r >> 7, j = r & 127;
      A[(size_t)row * AK + 32 + j] = (f16)cond[r];
    }
  }
}

// Convert weights fp32 -> f16, transposed per layer to (N x K) row-major.
__global__ void prep_weights(const float* __restrict__ W1, const float* __restrict__ W2,
                             const float* __restrict__ W3,
                             f16* __restrict__ W1t, f16* __restrict__ W2t,
                             f16* __restrict__ W3t)
{
  const int N2 = 6 << 20;              // W2t elems: 6*1024*1024
  const int N1 = N2 + 6 * 1024 * 160;  // + W1t
  const int N3 = N1 + 6 * 64 * 1024;   // + W3t
  for (int i = blockIdx.x * blockDim.x + threadIdx.x; i < N3;
       i += gridDim.x * blockDim.x) {
    if (i < N2) {
      int l = i >> 20, r = i & 0xFFFFF, n = r >> 10, k = r & 1023;
      W2t[i] = (f16)W2[((size_t)l << 20) + ((size_t)k << 10) + n];
    } else if (i < N1) {
      int t = i - N2;
      int l = t / 163840, r = t % 163840, n = r / 160, k = r % 160;
      W1t[t] = (f16)W1[(size_t)l * 163840 + (size_t)k * 1024 + n];
    } else {
      int t = i - N1;
      int l = t >> 16, r = t & 0xFFFF, n = r >> 10, k = r & 1023;
      W3t[t] = (f16)W3[((size_t)l << 16) + ((size_t)k << 6) + n];
    }
  }
}

// ---------------------------------------------------------------------------
// GEMM (relu): C[M x 1024] = relu(A[M x K] @ Wt^T + bias), C in f16.
// 128x128 tile, BK=32, 4 waves, each 64x64 (4x4 of 16x16x32 MFMA). m97 recipe.
// ---------------------------------------------------------------------------
__global__ __launch_bounds__(256, 2)
void gemm12(const f16* __restrict__ A, const int K,
            const f16* __restrict__ Wt,       // 1024 x K (pre-transposed)
            const float* __restrict__ bias,
            f16* __restrict__ C)
{
  __shared__ __align__(16) f16 As[128 * 32];
  __shared__ __align__(16) f16 Bs[128 * 32];
  const int tid  = threadIdx.x;
  const int wave = tid >> 6;
  const int lane = tid & 63;
  const int c15  = lane & 15;
  const int quad = lane >> 4;
  const int wm = (wave & 1) * 64;
  const int wn = (wave >> 1) * 64;
  const long rowStart = (long)blockIdx.y * 128;
  const long colStart = (long)blockIdx.x * 128;

  const f16* Ab = A  + rowStart * K;
  const f16* Bb = Wt + colStart * K;

  // staging: 512 16B-chunks per tile, 2 issues of 256 per buffer
  const int c0 = tid,        r0 = c0 >> 2, kc0 = (c0 & 3) * 8;
  const int c1 = 256 + tid,  r1 = c1 >> 2, kc1 = (c1 & 3) * 8;
  f16* AsW0 = As + (wave * 64) * 8;          // wave-uniform LDS bases
  f16* AsW1 = As + (256 + wave * 64) * 8;
  f16* BsW0 = Bs + (wave * 64) * 8;
  f16* BsW1 = Bs + (256 + wave * 64) * 8;

  f32x4 acc[4][4] = {};

  for (int k0 = 0; k0 < K; k0 += 32) {
    __syncthreads();
    async_copy16(Ab + (long)r0 * K + k0 + kc0, AsW0);
    async_copy16(Ab + (long)r1 * K + k0 + kc1, AsW1);
    async_copy16(Bb + (long)r0 * K + k0 + kc0, BsW0);
    async_copy16(Bb + (long)r1 * K + k0 + kc1, BsW1);
    __syncthreads();   // compiler emits vmcnt(0) drain before barrier

    f16x8 a[4], b[4];
#pragma unroll
    for (int mi = 0; mi < 4; ++mi)
      a[mi] = *(const f16x8*)&As[(wm + mi * 16 + c15) * 32 + quad * 8];
#pragma unroll
    for (int ni = 0; ni < 4; ++ni)
      b[ni] = *(const f16x8*)&Bs[(wn + ni * 16 + c15) * 32 + quad * 8];
#pragma unroll
    for (int mi = 0; mi < 4; ++mi)
#pragma unroll
      for (int ni = 0; ni < 4; ++ni)
        acc[mi][ni] = __builtin_amdgcn_mfma_f32_16x16x32_f16(a[mi], b[ni], acc[mi][ni], 0, 0, 0);
  }

  // epilogue: bias + relu + f16 store. C/D layout: col=lane&15, row=quad*4+r
#pragma unroll
  for (int ni = 0; ni < 4; ++ni) {
    const long gn = colStart + wn + ni * 16 + c15;
    const float bv = bias[gn];
#pragma unroll
    for (int mi = 0; mi < 4; ++mi) {
#pragma unroll
      for (int r = 0; r < 4; ++r) {
        const long gm = rowStart + wm + mi * 16 + quad * 4 + r;
        float v = acc[mi][ni][r] + bv;
        v = fmaxf(v, 0.0f);
        C[gm * HID + gn] = (f16)v;
      }
    }
  }
}

// ---------------------------------------------------------------------------
// GEMM3 (N=64) + coupling epilogue. BM=64, 4 waves x (16 rows x 64 cols).
// s-col j and t-col j+32 land in the same lane & same reg slot -> no shuffles.
// Writes y to z (fp32, in d_out) and to Anext[:, :32] (f16, next layer input).
// log_det[row] += sum_j tanh(params[row][j]) via 16-lane shfl_xor reduce.
// ---------------------------------------------------------------------------
__global__ __launch_bounds__(256, 4)
void gemm3_coupling(const f16* __restrict__ X2, const f16* __restrict__ W3t,
                    const float* __restrict__ b3, float* __restrict__ z,
                    float* __restrict__ log_det, f16* __restrict__ Anext,
                    const int maskoff)
{
  __shared__ __align__(16) f16 As[64 * 32];
  __shared__ __align__(16) f16 Bs[64 * 32];
  const int tid = threadIdx.x;
  const int wave = tid >> 6, lane = tid & 63;
  const int c15 = lane & 15, quad = lane >> 4;
  const long rowStart = (long)blockIdx.x * 64;

  const f16* Ab = X2 + rowStart * HID;
  const int r0 = tid >> 2, kc0 = (tid & 3) * 8;  // 256 chunks = 1 issue
  f16* AsW = As + wave * 512;
  f16* BsW = Bs + wave * 512;

  f32x4 acc[4] = {};

  for (int k0 = 0; k0 < HID; k0 += 32) {
    __syncthreads();
    async_copy16(Ab  + (long)r0 * HID + k0 + kc0, AsW);
    async_copy16(W3t + (long)r0 * HID + k0 + kc0, BsW);
    __syncthreads();
    f16x8 a = *(const f16x8*)&As[(wave * 16 + c15) * 32 + quad * 8];
#pragma unroll
    for (int ni = 0; ni < 4; ++ni) {
      f16x8 b = *(const f16x8*)&Bs[(ni * 16 + c15) * 32 + quad * 8];
      acc[ni] = __builtin_amdgcn_mfma_f32_16x16x32_f16(a, b, acc[ni], 0, 0, 0);
    }
  }

  float sp[4] = {0.0f, 0.0f, 0.0f, 0.0f};
#pragma unroll
  for (int ni = 0; ni < 2; ++ni) {
    const int j = ni * 16 + c15;          // s-column 0..31
    const float bs = b3[j];
    const float bt = b3[32 + j];
#pragma unroll
    for (int r = 0; r < 4; ++r) {
      const long gm = rowStart + wave * 16 + quad * 4 + r;
      const float sv = acc[ni][r] + bs;
      const float e2 = __expf(2.0f * sv);            // tanh via exp
      const float s  = 1.0f - 2.0f / (e2 + 1.0f);
      const float tv = acc[ni + 2][r] + bt;
      const float m  = z[gm * 64 + maskoff + j];
      const float y  = fmaf(m, __expf(s), tv);
      z[gm * 64 + maskoff + j] = y;
      Anext[gm * AK + j] = (f16)y;   // next layer's unmasked input, in order
      sp[r] += s;
    }
  }
#pragma unroll
  for (int r = 0; r < 4; ++r) {
    float v = sp[r];
    v += __shfl_xor(v, 1);
    v += __shfl_xor(v, 2);
    v += __shfl_xor(v, 4);
    v += __shfl_xor(v, 8);
    if (c15 == 0) {
      const long gm = rowStart + wave * 16 + quad * 4 + r;
      log_det[gm] += v;   // only this thread touches this row this layer
    }
  }
}

// ---------------------------------------------------------------------------
extern "C" void kernel_launch(void* const* d_in, const int* in_sizes, int n_in,
                              void* d_out, int out_size, void* d_ws, size_t ws_size,
                              hipStream_t stream) {
  (void)in_sizes; (void)n_in; (void)out_size; (void)ws_size;
  const float* T    = (const float*)d_in[0];
  const float* cond = (const float*)d_in[1];
  const float* W1   = (const float*)d_in[2];
  const float* b1   = (const float*)d_in[3];
  const float* W2   = (const float*)d_in[4];
  const float* b2   = (const float*)d_in[5];
  const float* W3   = (const float*)d_in[6];
  const float* b3   = (const float*)d_in[7];

  float* z  = (float*)d_out;                 // B x 64 working state = output
  float* ld = z + (size_t)NB * 64;           // B log_det

  f16* A   = (f16*)d_ws;                     // B x 160
  f16* X1  = A   + (size_t)NB * AK;          // B x 1024
  f16* X2  = X1  + (size_t)NB * HID;         // B x 1024
  f16* W1t = X2  + (size_t)NB * HID;         // 6 x 1024 x 160
  f16* W2t = W1t + (size_t)6 * 1024 * 160;   // 6 x 1024 x 1024
  f16* W3t = W2t + ((size_t)6 << 20);        // 6 x 64 x 1024

  prep_batch<<<2048, 256, 0, stream>>>(T, cond, z, ld, A);
  prep_weights<<<2048, 256, 0, stream>>>(W1, W2, W3, W1t, W2t, W3t);

  const dim3 g12(HID / 128, NB / 128);       // (8, 256)
  for (int l = 0; l < LAYERS; ++l) {
    gemm12<<<g12, 256, 0, stream>>>(A, AK, W1t + (size_t)l * 1024 * 160,
                                    b1 + l * 1024, X1);
    gemm12<<<g12, 256, 0, stream>>>(X1, HID, W2t + ((size_t)l << 20),
                                    b2 + l * 1024, X2);
    const int maskoff = (l & 1) ? 32 : 0;
    gemm3_coupling<<<NB / 64, 256, 0, stream>>>(X2, W3t + (size_t)l * 64 * 1024,
                                                b3 + l * 64, z, ld, A, maskoff);
  }
}

// Round 2
// 931.749 us; speedup vs baseline: 1.0538x; 1.0538x over previous
//
#include <hip/hip_runtime.h>
#include <hip/hip_fp16.h>
#include <stdint.h>

typedef _Float16 f16;
typedef _Float16 f16x8 __attribute__((ext_vector_type(8)));
typedef float f32x4 __attribute__((ext_vector_type(4)));

#define NB 32768      // batch
#define LAYERS 6
#define AK 160        // HALF + COND
#define HID 1024

// async global->LDS, 16B per lane. LDS dest is wave-uniform base + lane*16.
__device__ __forceinline__ void async_copy16(const void* g, void* l) {
  __builtin_amdgcn_global_load_lds(
      (const __attribute__((address_space(1))) void*)g,
      (__attribute__((address_space(3))) void*)l, 16, 0, 0);
}

// ---------------------------------------------------------------------------
// prep: z = T (fp32 working state lives in d_out), log_det = 0,
// A[:, :32] = f16(T[:, 32:]) (layer0 unmasked), A[:, 32:160] = f16(cond)
// ---------------------------------------------------------------------------
__global__ void prep_batch(const float* __restrict__ T, const float* __restrict__ cond,
                           float* __restrict__ z, float* __restrict__ ld,
                           f16* __restrict__ A)
{
  const int S1 = NB * 64;
  const int S2 = S1 + NB;
  const int S3 = S2 + NB * 32;
  const int S4 = S3 + NB * 128;
  for (int i = blockIdx.x * blockDim.x + threadIdx.x; i < S4;
       i += gridDim.x * blockDim.x) {
    if (i < S1) {
      z[i] = T[i];
    } else if (i < S2) {
      ld[i - S1] = 0.0f;
    } else if (i < S3) {
      int r = i - S2;
      int row = r >> 5, j = r & 31;
      A[(size_t)row * AK + j] = (f16)T[row * 64 + 32 + j];
    } else {
      int r = i - S3;
      int row = r >> 7, j = r & 127;
      A[(size_t)row * AK + 32 + j] = (f16)cond[r];
    }
  }
}

// Convert weights fp32 -> f16, transposed per layer to (N x K) row-major.
__global__ void prep_weights(const float* __restrict__ W1, const float* __restrict__ W2,
                             const float* __restrict__ W3,
                             f16* __restrict__ W1t, f16* __restrict__ W2t,
                             f16* __restrict__ W3t)
{
  const int N2 = 6 << 20;              // W2t elems: 6*1024*1024
  const int N1 = N2 + 6 * 1024 * 160;  // + W1t
  const int N3 = N1 + 6 * 64 * 1024;   // + W3t
  for (int i = blockIdx.x * blockDim.x + threadIdx.x; i < N3;
       i += gridDim.x * blockDim.x) {
    if (i < N2) {
      int l = i >> 20, r = i & 0xFFFFF, n = r >> 10, k = r & 1023;
      W2t[i] = (f16)W2[((size_t)l << 20) + ((size_t)k << 10) + n];
    } else if (i < N1) {
      int t = i - N2;
      int l = t / 163840, r = t % 163840, n = r / 160, k = r % 160;
      W1t[t] = (f16)W1[(size_t)l * 163840 + (size_t)k * 1024 + n];
    } else {
      int t = i - N1;
      int l = t >> 16, r = t & 0xFFFF, n = r >> 10, k = r & 1023;
      W3t[t] = (f16)W3[((size_t)l << 16) + ((size_t)k << 6) + n];
    }
  }
}

// ---------------------------------------------------------------------------
// GEMM (relu): C[M x 1024] = relu(A[M x K] @ Wt^T + bias), C in f16.
// 256x128 block tile, BK=32, 4 waves, wave-tile 128x64 (8x4 of 16x16x32 MFMA).
// 43.7 FLOP per LDS byte -> LDS read pipe supports ~91% of MFMA peak (vs 66%
// for the old 64x64 wave tile). XCD swizzle: blk&7 = XCD owns 16 row-groups,
// cols fastest -> A re-reads served from that XCD's L2.
// ---------------------------------------------------------------------------
__global__ __launch_bounds__(256, 2)
void gemm12(const f16* __restrict__ A, const int K,
            const f16* __restrict__ Wt,       // 1024 x K (pre-transposed)
            const float* __restrict__ bias,
            f16* __restrict__ C)
{
  __shared__ __align__(16) f16 As[256 * 32];
  __shared__ __align__(16) f16 Bs[128 * 32];
  const int tid  = threadIdx.x;
  const int wave = tid >> 6;
  const int lane = tid & 63;
  const int c15  = lane & 15;
  const int quad = lane >> 4;
  const int wm = (wave & 1) * 128;
  const int wn = (wave >> 1) * 64;

  // XCD-aware swizzle (grid = 1024 = 128 row-groups x 8 col-blocks)
  const int b = blockIdx.x;
  const int x = b & 7, i = b >> 3;
  const long rowStart = (long)(x * 16 + (i >> 3)) * 256;
  const long colStart = (long)(i & 7) * 128;

  const f16* Ab = A  + rowStart * K;
  const f16* Bb = Wt + colStart * K;

  // staging: A = 1024 16B-chunks (4 issues), B = 512 chunks (2 issues)
  const int r0 = tid >> 2, kc0 = (tid & 3) * 8;
  f16* AsW[4]; f16* BsW[2];
#pragma unroll
  for (int q = 0; q < 4; ++q) AsW[q] = As + (q * 256 + wave * 64) * 8;
#pragma unroll
  for (int q = 0; q < 2; ++q) BsW[q] = Bs + (q * 256 + wave * 64) * 8;

  f32x4 acc[8][4] = {};

  for (int k0 = 0; k0 < K; k0 += 32) {
    __syncthreads();
#pragma unroll
    for (int q = 0; q < 4; ++q)
      async_copy16(Ab + (long)(q * 64 + r0) * K + k0 + kc0, AsW[q]);
#pragma unroll
    for (int q = 0; q < 2; ++q)
      async_copy16(Bb + (long)(q * 64 + r0) * K + k0 + kc0, BsW[q]);
    __syncthreads();   // vmcnt(0) drain

    f16x8 a[8], bf[4];
#pragma unroll
    for (int mi = 0; mi < 8; ++mi)
      a[mi] = *(const f16x8*)&As[(wm + mi * 16 + c15) * 32 + quad * 8];
#pragma unroll
    for (int ni = 0; ni < 4; ++ni)
      bf[ni] = *(const f16x8*)&Bs[(wn + ni * 16 + c15) * 32 + quad * 8];
#pragma unroll
    for (int mi = 0; mi < 8; ++mi)
#pragma unroll
      for (int ni = 0; ni < 4; ++ni)
        acc[mi][ni] = __builtin_amdgcn_mfma_f32_16x16x32_f16(a[mi], bf[ni], acc[mi][ni], 0, 0, 0);
  }

  // epilogue: bias + relu + f16 store. C/D layout: col=lane&15, row=quad*4+r
#pragma unroll
  for (int ni = 0; ni < 4; ++ni) {
    const long gn = colStart + wn + ni * 16 + c15;
    const float bv = bias[gn];
#pragma unroll
    for (int mi = 0; mi < 8; ++mi) {
#pragma unroll
      for (int r = 0; r < 4; ++r) {
        const long gm = rowStart + wm + mi * 16 + quad * 4 + r;
        float v = acc[mi][ni][r] + bv;
        v = fmaxf(v, 0.0f);
        C[gm * HID + gn] = (f16)v;
      }
    }
  }
}

// ---------------------------------------------------------------------------
// GEMM3 (N=64) + coupling epilogue. BM=128, 4 waves, wave-tile 32x64.
// s-col j and t-col j+32 land in the same lane & same reg slot -> no shuffles.
// Writes y to z (fp32, in d_out) and to Anext[:, :32] (f16, next layer input).
// log_det[row] += sum_j tanh(params[row][j]) via 16-lane shfl_xor reduce.
// ---------------------------------------------------------------------------
__global__ __launch_bounds__(256, 4)
void gemm3_coupling(const f16* __restrict__ X2, const f16* __restrict__ W3t,
                    const float* __restrict__ b3, float* __restrict__ z,
                    float* __restrict__ log_det, f16* __restrict__ Anext,
                    const int maskoff)
{
  __shared__ __align__(16) f16 As[128 * 32];
  __shared__ __align__(16) f16 Bs[64 * 32];
  const int tid = threadIdx.x;
  const int wave = tid >> 6, lane = tid & 63;
  const int c15 = lane & 15, quad = lane >> 4;
  const int wm = wave * 32;
  const long rowStart = (long)blockIdx.x * 128;

  const f16* Ab = X2 + rowStart * HID;
  const int r0 = tid >> 2, kc0 = (tid & 3) * 8;
  f16* AsW0 = As + (wave * 64) * 8;
  f16* AsW1 = As + (256 + wave * 64) * 8;
  f16* BsW  = Bs + (wave * 64) * 8;

  f32x4 acc[2][4] = {};

  for (int k0 = 0; k0 < HID; k0 += 32) {
    __syncthreads();
    async_copy16(Ab  + (long)r0 * HID + k0 + kc0, AsW0);
    async_copy16(Ab  + (long)(64 + r0) * HID + k0 + kc0, AsW1);
    async_copy16(W3t + (long)r0 * HID + k0 + kc0, BsW);
    __syncthreads();
    f16x8 a[2], bf[4];
#pragma unroll
    for (int mi = 0; mi < 2; ++mi)
      a[mi] = *(const f16x8*)&As[(wm + mi * 16 + c15) * 32 + quad * 8];
#pragma unroll
    for (int ni = 0; ni < 4; ++ni)
      bf[ni] = *(const f16x8*)&Bs[(ni * 16 + c15) * 32 + quad * 8];
#pragma unroll
    for (int mi = 0; mi < 2; ++mi)
#pragma unroll
      for (int ni = 0; ni < 4; ++ni)
        acc[mi][ni] = __builtin_amdgcn_mfma_f32_16x16x32_f16(a[mi], bf[ni], acc[mi][ni], 0, 0, 0);
  }

#pragma unroll
  for (int mi = 0; mi < 2; ++mi) {
    float sp[4] = {0.0f, 0.0f, 0.0f, 0.0f};
#pragma unroll
    for (int ni = 0; ni < 2; ++ni) {
      const int j = ni * 16 + c15;          // s-column 0..31
      const float bs = b3[j];
      const float bt = b3[32 + j];
#pragma unroll
      for (int r = 0; r < 4; ++r) {
        const long gm = rowStart + wm + mi * 16 + quad * 4 + r;
        const float sv = acc[mi][ni][r] + bs;
        const float e2 = __expf(2.0f * sv);            // tanh via exp
        const float s  = 1.0f - 2.0f / (e2 + 1.0f);
        const float tv = acc[mi][ni + 2][r] + bt;
        const float m  = z[gm * 64 + maskoff + j];
        const float y  = fmaf(m, __expf(s), tv);
        z[gm * 64 + maskoff + j] = y;
        Anext[gm * AK + j] = (f16)y;   // next layer's unmasked input
        sp[r] += s;
      }
    }
#pragma unroll
    for (int r = 0; r < 4; ++r) {
      float v = sp[r];
      v += __shfl_xor(v, 1);
      v += __shfl_xor(v, 2);
      v += __shfl_xor(v, 4);
      v += __shfl_xor(v, 8);
      if (c15 == 0) {
        const long gm = rowStart + wm + mi * 16 + quad * 4 + r;
        log_det[gm] += v;   // only this thread touches this row this layer
      }
    }
  }
}

// ---------------------------------------------------------------------------
extern "C" void kernel_launch(void* const* d_in, const int* in_sizes, int n_in,
                              void* d_out, int out_size, void* d_ws, size_t ws_size,
                              hipStream_t stream) {
  (void)in_sizes; (void)n_in; (void)out_size; (void)ws_size;
  const float* T    = (const float*)d_in[0];
  const float* cond = (const float*)d_in[1];
  const float* W1   = (const float*)d_in[2];
  const float* b1   = (const float*)d_in[3];
  const float* W2   = (const float*)d_in[4];
  const float* b2   = (const float*)d_in[5];
  const float* W3   = (const float*)d_in[6];
  const float* b3   = (const float*)d_in[7];

  float* z  = (float*)d_out;                 // B x 64 working state = output
  float* ld = z + (size_t)NB * 64;           // B log_det

  f16* A   = (f16*)d_ws;                     // B x 160
  f16* X1  = A   + (size_t)NB * AK;          // B x 1024
  f16* X2  = X1  + (size_t)NB * HID;         // B x 1024
  f16* W1t = X2  + (size_t)NB * HID;         // 6 x 1024 x 160
  f16* W2t = W1t + (size_t)6 * 1024 * 160;   // 6 x 1024 x 1024
  f16* W3t = W2t + ((size_t)6 << 20);        // 6 x 64 x 1024

  prep_batch<<<2048, 256, 0, stream>>>(T, cond, z, ld, A);
  prep_weights<<<2048, 256, 0, stream>>>(W1, W2, W3, W1t, W2t, W3t);

  const int g12 = (NB / 256) * (HID / 128);  // 1024 blocks
  for (int l = 0; l < LAYERS; ++l) {
    gemm12<<<g12, 256, 0, stream>>>(A, AK, W1t + (size_t)l * 1024 * 160,
                                    b1 + l * 1024, X1);
    gemm12<<<g12, 256, 0, stream>>>(X1, HID, W2t + ((size_t)l << 20),
                                    b2 + l * 1024, X2);
    const int maskoff = (l & 1) ? 32 : 0;
    gemm3_coupling<<<NB / 128, 256, 0, stream>>>(X2, W3t + (size_t)l * 64 * 1024,
                                                 b3 + l * 64, z, ld, A, maskoff);
  }
}

// Round 3
// 910.159 us; speedup vs baseline: 1.0788x; 1.0237x over previous
//
#include <hip/hip_runtime.h>
#include <hip/hip_fp16.h>
#include <stdint.h>

typedef _Float16 f16;
typedef _Float16 f16x8 __attribute__((ext_vector_type(8)));
typedef float f32x4 __attribute__((ext_vector_type(4)));

#define NB 32768      // batch
#define LAYERS 6
#define AK 160        // HALF + COND
#define HID 1024

// async global->LDS, 16B per lane. LDS dest is wave-uniform base + lane*16.
__device__ __forceinline__ void async_copy16(const void* g, void* l) {
  __builtin_amdgcn_global_load_lds(
      (const __attribute__((address_space(1))) void*)g,
      (__attribute__((address_space(3))) void*)l, 16, 0, 0);
}

// ---------------------------------------------------------------------------
// prep: z = T (fp32 working state lives in d_out), log_det = 0,
// A[:, :32] = f16(T[:, 32:]) (layer0 unmasked), A[:, 32:160] = f16(cond)
// ---------------------------------------------------------------------------
__global__ void prep_batch(const float* __restrict__ T, const float* __restrict__ cond,
                           float* __restrict__ z, float* __restrict__ ld,
                           f16* __restrict__ A)
{
  const int S1 = NB * 64;
  const int S2 = S1 + NB;
  const int S3 = S2 + NB * 32;
  const int S4 = S3 + NB * 128;
  for (int i = blockIdx.x * blockDim.x + threadIdx.x; i < S4;
       i += gridDim.x * blockDim.x) {
    if (i < S1) {
      z[i] = T[i];
    } else if (i < S2) {
      ld[i - S1] = 0.0f;
    } else if (i < S3) {
      int r = i - S2;
      int row = r >> 5, j = r & 31;
      A[(size_t)row * AK + j] = (f16)T[row * 64 + 32 + j];
    } else {
      int r = i - S3;
      int row = r >> 7, j = r & 127;
      A[(size_t)row * AK + 32 + j] = (f16)cond[r];
    }
  }
}

// Convert weights fp32 -> f16, transposed per layer to (N x K) row-major.
__global__ void prep_weights(const float* __restrict__ W1, const float* __restrict__ W2,
                             const float* __restrict__ W3,
                             f16* __restrict__ W1t, f16* __restrict__ W2t,
                             f16* __restrict__ W3t)
{
  const int N2 = 6 << 20;              // W2t elems: 6*1024*1024
  const int N1 = N2 + 6 * 1024 * 160;  // + W1t
  const int N3 = N1 + 6 * 64 * 1024;   // + W3t
  for (int i = blockIdx.x * blockDim.x + threadIdx.x; i < N3;
       i += gridDim.x * blockDim.x) {
    if (i < N2) {
      int l = i >> 20, r = i & 0xFFFFF, n = r >> 10, k = r & 1023;
      W2t[i] = (f16)W2[((size_t)l << 20) + ((size_t)k << 10) + n];
    } else if (i < N1) {
      int t = i - N2;
      int l = t / 163840, r = t % 163840, n = r / 160, k = r % 160;
      W1t[t] = (f16)W1[(size_t)l * 163840 + (size_t)k * 1024 + n];
    } else {
      int t = i - N1;
      int l = t >> 16, r = t & 0xFFFF, n = r >> 10, k = r & 1023;
      W3t[t] = (f16)W3[((size_t)l << 16) + ((size_t)k << 6) + n];
    }
  }
}

// ---------------------------------------------------------------------------
// GEMM (relu): C[M x 1024] = relu(A[M x K] @ Wt^T + bias), C in f16.
// 256x128 block tile, BK=32, 4 waves, wave-tile 128x64.
// Software pipeline: LDS double-buffer, ONE barrier per k-step, prefetch of
// tile k+1 issued right after the barrier -> vmcnt(0) drain happens a full
// compute phase (~620 cyc) after issue, hiding L2/HBM latency.
// XOR bank swizzle: lane fetches global chunk (kc ^ ((row>>1)&3)) so the
// forced global_load_lds layout becomes conflict-free for ds_read_b128
// (writes stay lane-consecutive = perfect; reads spread over all 32 banks).
// ---------------------------------------------------------------------------
__global__ __launch_bounds__(256, 2)
void gemm12(const f16* __restrict__ A, const int K,
            const f16* __restrict__ Wt,       // 1024 x K (pre-transposed)
            const float* __restrict__ bias,
            f16* __restrict__ C)
{
  __shared__ __align__(16) f16 As[2][256 * 32];
  __shared__ __align__(16) f16 Bs[2][128 * 32];
  const int tid  = threadIdx.x;
  const int wave = tid >> 6;
  const int lane = tid & 63;
  const int c15  = lane & 15;
  const int quad = lane >> 4;
  const int wm = (wave & 1) * 128;
  const int wn = (wave >> 1) * 64;

  // XCD-aware swizzle (grid = 1024 = 8 XCDs x 16 row-groups x 8 col-blocks)
  const int b = blockIdx.x;
  const int x = b & 7, i = b >> 3;
  const long rowStart = (long)(x * 16 + (i >> 3)) * 256;
  const long colStart = (long)(i & 7) * 128;

  const f16* Ab = A  + rowStart * K;
  const f16* Bb = Wt + colStart * K;

  // staging: lane's LDS slot is fixed; fetch the XOR-permuted global chunk
  const int ra  = tid >> 2;
  const int kca = (((tid & 3) ^ ((ra >> 1) & 3))) * 8;

  f32x4 acc[8][4] = {};
  const int nK = K >> 5;

  auto stage = [&](int kt, int sel) {
    const long ko = (long)kt * 32;
    f16* as = &As[sel][0];
    f16* bs = &Bs[sel][0];
#pragma unroll
    for (int q = 0; q < 4; ++q)
      async_copy16(Ab + (long)(q * 64 + ra) * K + ko + kca,
                   as + (q * 256 + wave * 64) * 8);
#pragma unroll
    for (int q = 0; q < 2; ++q)
      async_copy16(Bb + (long)(q * 64 + ra) * K + ko + kca,
                   bs + (q * 256 + wave * 64) * 8);
  };

  stage(0, 0);
  for (int kt = 0; kt < nK; ++kt) {
    __syncthreads();                      // drains tile-kt loads (issued last iter)
    if (kt + 1 < nK) stage(kt + 1, (kt + 1) & 1);
    const f16* as = &As[kt & 1][0];
    const f16* bs = &Bs[kt & 1][0];

    f16x8 a[8], bf[4];
#pragma unroll
    for (int mi = 0; mi < 8; ++mi) {
      const int R = wm + mi * 16 + c15;
      a[mi] = *(const f16x8*)&as[R * 32 + ((quad ^ ((R >> 1) & 3)) << 3)];
    }
#pragma unroll
    for (int ni = 0; ni < 4; ++ni) {
      const int R = wn + ni * 16 + c15;
      bf[ni] = *(const f16x8*)&bs[R * 32 + ((quad ^ ((R >> 1) & 3)) << 3)];
    }
#pragma unroll
    for (int mi = 0; mi < 8; ++mi)
#pragma unroll
      for (int ni = 0; ni < 4; ++ni)
        acc[mi][ni] = __builtin_amdgcn_mfma_f32_16x16x32_f16(a[mi], bf[ni], acc[mi][ni], 0, 0, 0);
  }

  // epilogue: bias + relu + f16 store. C/D layout: col=lane&15, row=quad*4+r
#pragma unroll
  for (int ni = 0; ni < 4; ++ni) {
    const long gn = colStart + wn + ni * 16 + c15;
    const float bv = bias[gn];
#pragma unroll
    for (int mi = 0; mi < 8; ++mi) {
#pragma unroll
      for (int r = 0; r < 4; ++r) {
        const long gm = rowStart + wm + mi * 16 + quad * 4 + r;
        float v = acc[mi][ni][r] + bv;
        v = fmaxf(v, 0.0f);
        C[gm * HID + gn] = (f16)v;
      }
    }
  }
}

// ---------------------------------------------------------------------------
// GEMM3 (N=64) + coupling epilogue. BM=128, 4 waves, wave-tile 32x64.
// Same pipeline + swizzle. s-col j and t-col j+32 share lane & reg slot.
// Writes y to z (fp32, in d_out) and to Anext[:, :32] (f16, next layer input).
// ---------------------------------------------------------------------------
__global__ __launch_bounds__(256, 4)
void gemm3_coupling(const f16* __restrict__ X2, const f16* __restrict__ W3t,
                    const float* __restrict__ b3, float* __restrict__ z,
                    float* __restrict__ log_det, f16* __restrict__ Anext,
                    const int maskoff)
{
  __shared__ __align__(16) f16 As[2][128 * 32];
  __shared__ __align__(16) f16 Bs[2][64 * 32];
  const int tid = threadIdx.x;
  const int wave = tid >> 6, lane = tid & 63;
  const int c15 = lane & 15, quad = lane >> 4;
  const int wm = wave * 32;
  const long rowStart = (long)blockIdx.x * 128;

  const f16* Ab = X2 + rowStart * HID;
  const int ra  = tid >> 2;
  const int kca = (((tid & 3) ^ ((ra >> 1) & 3))) * 8;

  f32x4 acc[2][4] = {};

  auto stage = [&](int kt, int sel) {
    const long ko = (long)kt * 32;
    f16* as = &As[sel][0];
    f16* bs = &Bs[sel][0];
#pragma unroll
    for (int q = 0; q < 2; ++q)
      async_copy16(Ab + (long)(q * 64 + ra) * HID + ko + kca,
                   as + (q * 256 + wave * 64) * 8);
    async_copy16(W3t + (long)ra * HID + ko + kca,
                 bs + (wave * 64) * 8);
  };

  stage(0, 0);
  for (int kt = 0; kt < 32; ++kt) {
    __syncthreads();
    if (kt + 1 < 32) stage(kt + 1, (kt + 1) & 1);
    const f16* as = &As[kt & 1][0];
    const f16* bs = &Bs[kt & 1][0];

    f16x8 a[2], bf[4];
#pragma unroll
    for (int mi = 0; mi < 2; ++mi) {
      const int R = wm + mi * 16 + c15;
      a[mi] = *(const f16x8*)&as[R * 32 + ((quad ^ ((R >> 1) & 3)) << 3)];
    }
#pragma unroll
    for (int ni = 0; ni < 4; ++ni) {
      const int R = ni * 16 + c15;
      bf[ni] = *(const f16x8*)&bs[R * 32 + ((quad ^ ((R >> 1) & 3)) << 3)];
    }
#pragma unroll
    for (int mi = 0; mi < 2; ++mi)
#pragma unroll
      for (int ni = 0; ni < 4; ++ni)
        acc[mi][ni] = __builtin_amdgcn_mfma_f32_16x16x32_f16(a[mi], bf[ni], acc[mi][ni], 0, 0, 0);
  }

#pragma unroll
  for (int mi = 0; mi < 2; ++mi) {
    float sp[4] = {0.0f, 0.0f, 0.0f, 0.0f};
#pragma unroll
    for (int ni = 0; ni < 2; ++ni) {
      const int j = ni * 16 + c15;          // s-column 0..31
      const float bs = b3[j];
      const float bt = b3[32 + j];
#pragma unroll
      for (int r = 0; r < 4; ++r) {
        const long gm = rowStart + wm + mi * 16 + quad * 4 + r;
        const float sv = acc[mi][ni][r] + bs;
        const float e2 = __expf(2.0f * sv);            // tanh via exp
        const float s  = 1.0f - 2.0f / (e2 + 1.0f);
        const float tv = acc[mi][ni + 2][r] + bt;
        const float m  = z[gm * 64 + maskoff + j];
        const float y  = fmaf(m, __expf(s), tv);
        z[gm * 64 + maskoff + j] = y;
        Anext[gm * AK + j] = (f16)y;   // next layer's unmasked input
        sp[r] += s;
      }
    }
#pragma unroll
    for (int r = 0; r < 4; ++r) {
      float v = sp[r];
      v += __shfl_xor(v, 1);
      v += __shfl_xor(v, 2);
      v += __shfl_xor(v, 4);
      v += __shfl_xor(v, 8);
      if (c15 == 0) {
        const long gm = rowStart + wm + mi * 16 + quad * 4 + r;
        log_det[gm] += v;   // only this thread touches this row this layer
      }
    }
  }
}

// ---------------------------------------------------------------------------
extern "C" void kernel_launch(void* const* d_in, const int* in_sizes, int n_in,
                              void* d_out, int out_size, void* d_ws, size_t ws_size,
                              hipStream_t stream) {
  (void)in_sizes; (void)n_in; (void)out_size; (void)ws_size;
  const float* T    = (const float*)d_in[0];
  const float* cond = (const float*)d_in[1];
  const float* W1   = (const float*)d_in[2];
  const float* b1   = (const float*)d_in[3];
  const float* W2   = (const float*)d_in[4];
  const float* b2   = (const float*)d_in[5];
  const float* W3   = (const float*)d_in[6];
  const float* b3   = (const float*)d_in[7];

  float* z  = (float*)d_out;                 // B x 64 working state = output
  float* ld = z + (size_t)NB * 64;           // B log_det

  f16* A   = (f16*)d_ws;                     // B x 160
  f16* X1  = A   + (size_t)NB * AK;          // B x 1024
  f16* X2  = X1  + (size_t)NB * HID;         // B x 1024
  f16* W1t = X2  + (size_t)NB * HID;         // 6 x 1024 x 160
  f16* W2t = W1t + (size_t)6 * 1024 * 160;   // 6 x 1024 x 1024
  f16* W3t = W2t + ((size_t)6 << 20);        // 6 x 64 x 1024

  prep_batch<<<2048, 256, 0, stream>>>(T, cond, z, ld, A);
  prep_weights<<<2048, 256, 0, stream>>>(W1, W2, W3, W1t, W2t, W3t);

  const int g12 = (NB / 256) * (HID / 128);  // 1024 blocks
  for (int l = 0; l < LAYERS; ++l) {
    gemm12<<<g12, 256, 0, stream>>>(A, AK, W1t + (size_t)l * 1024 * 160,
                                    b1 + l * 1024, X1);
    gemm12<<<g12, 256, 0, stream>>>(X1, HID, W2t + ((size_t)l << 20),
                                    b2 + l * 1024, X2);
    const int maskoff = (l & 1) ? 32 : 0;
    gemm3_coupling<<<NB / 128, 256, 0, stream>>>(X2, W3t + (size_t)l * 64 * 1024,
                                                 b3 + l * 64, z, ld, A, maskoff);
  }
}